// Round 2
// baseline (319.858 us; speedup 1.0000x reference)
//
#include <hip/hip_runtime.h>
#include <hip/hip_bf16.h>

#define NPTS 150
#define KP   168          // padded K for MFMA; 5 K-steps of 32 cover 0..159
#define NPAR 193
#define OSTR 388

// bf16 transposed activation buffers, element offsets into sT
#define H1T  0            // [11][168]  rows 0..9 = h1^T, row 10 = ones (db2)
#define H2T  1848         // [11][168]  rows 0..9 = h2^T, row 10 = ones (db3)
#define XT   3696         // [5][168]   rows 0..3 = x^T,  row 4  = ones (db1)
#define DZ2T 4536         // [10][168]
#define DZ1T 6216         // [10][168]
#define DLT  7896         // [3][168]
#define TTOT 8400

typedef __attribute__((ext_vector_type(8))) short short8;
typedef __attribute__((ext_vector_type(4))) float f32x4;
typedef __attribute__((ext_vector_type(2))) float f32x2;

__constant__ float LRS[6] = {0.001f, 0.01f, 0.05f, 0.1f, 0.5f, 1.0f};

// Persistent blocks: 2048 blocks x (Bn/2048) MLPs each, grid-stride.
// Rationale (round-1 counters): VALUBusy 60%, MfmaUtil 1.8%, HBM 7%,
// occupancy 31% -> issue-bound with big idle gaps from per-block startup
// (param/grad load latency) and one-shot setup (zero-fill, x^T fill).
// The loop amortizes setup, prefetches next MLP's params during current
// compute, and the hot loops use float2 (v_pk_fma_f32) with ds_read_b64
// row-major LDS reads for BOTH h2 and dz1.
__global__ __launch_bounds__(192)
__attribute__((amdgpu_waves_per_eu(2, 4)))
void mlp_kernelA(
    const float* __restrict__ W1, const float* __restrict__ b1,
    const float* __restrict__ W2, const float* __restrict__ b2,
    const float* __restrict__ W3, const float* __restrict__ b3,
    const float* __restrict__ G1, const float* __restrict__ G2,
    const float* __restrict__ G3, const float* __restrict__ G4,
    const float* __restrict__ G5, const float* __restrict__ G6,
    const float* __restrict__ dx, const float* __restrict__ fv,
    const int* __restrict__ dy, const int* __restrict__ stepsz,
    float* __restrict__ out, float* __restrict__ slots,
    int Bn, int storeMode)
{
    const int t    = threadIdx.x;
    const int lane = t & 63;
    const int w    = t >> 6;

    __shared__ alignas(16) __hip_bfloat16 sT[TTOT];
    __shared__ alignas(16) float sP[200];
    __shared__ float red[8];

    // ---- one-time: zero the whole bf16 T-buffer (pad cols MUST be finite
    //      zeros: uninitialized LDS as bf16 can be Inf/NaN -> NaN in MFMA) ----
    {
        f32x4 z = {0.f, 0.f, 0.f, 0.f};
        f32x4* p = (f32x4*)sT;                 // 8400 bf16 = 1050 x 16B
        for (int i = t; i < 1050; i += 192) p[i] = z;
    }
    // ---- one-time: ones rows + x^T fill (x is the same for every MLP) ----
    if (t < KP) {
        __hip_bfloat16 one = __float2bfloat16(1.0f);
        sT[H1T + 10*KP + t] = one;
        sT[H2T + 10*KP + t] = one;
        sT[XT  +  4*KP + t] = one;
    }
    for (int i = t; i < 600; i += 192) {
        int n = i >> 2, f = i & 3;
        sT[XT + f*KP + n] = __float2bfloat16(dx[i]);
    }

    // ---- one-time: per-thread data point in registers ----
    const bool act = (t < NPTS);
    const int  nc  = act ? t : 0;
    const f32x4 xv = ((const f32x4*)dx)[nc];
    const int   yv = dy[nc];

    // ---- one-time: per-thread param/grad pointers (thread t owns index t) ----
    const float *ppar, *pgrad; int pstr;
    if      (t < 40)  { ppar = W1 + t;        pgrad = G1 + t;        pstr = 40;  }
    else if (t < 50)  { ppar = b1 + (t-40);   pgrad = G2 + (t-40);   pstr = 10;  }
    else if (t < 150) { ppar = W2 + (t-50);   pgrad = G3 + (t-50);   pstr = 100; }
    else if (t < 160) { ppar = b2 + (t-150);  pgrad = G4 + (t-150);  pstr = 10;  }
    else if (t < 190) { ppar = W3 + (t-160);  pgrad = G5 + (t-160);  pstr = 30;  }
    else              { ppar = b3 + (t-190);  pgrad = G6 + (t-190);  pstr = 3;   }

    // ---- one-time: per-wave MFMA tile config (loop-invariant) ----
    const short* sTs = reinterpret_cast<const short*>(sT);
    const int mrow = lane & 15, q = lane >> 4;
    int abase, arows, bbase, bcols, woff, nW, boff;
    if      (w == 0) { abase=DZ2T; arows=10; bbase=H1T; bcols=11; woff=50;  nW=10; boff=150; }
    else if (w == 1) { abase=DZ1T; arows=10; bbase=XT;  bcols=5;  woff=0;   nW=4;  boff=40;  }
    else             { abase=DLT;  arows=3;  bbase=H2T; bcols=11; woff=160; nW=10; boff=190; }
    const int ar = (mrow < arows) ? mrow : 0;
    const int br = (mrow < bcols) ? mrow : 0;
    const short* aptr = sTs + abase + ar*KP;
    const short* bptr = sTs + bbase + br*KP;
    int  offv[4]; bool valid[4];
    #pragma unroll
    for (int r = 0; r < 4; r++) {
        int row = q*4 + r;
        valid[r] = (row < arows) && (mrow < bcols);
        offv[r]  = (mrow < nW) ? (woff + row*nW + mrow) : (boff + row);
    }

    const f32x2* sP2 = (const f32x2*)sP;
    const f32x2  x01 = {xv.x, xv.y}, x23 = {xv.z, xv.w};

    const int stride = gridDim.x;

    // ---- initial prefetch ----
    size_t mi0 = (size_t)blockIdx.x;
    float pv = ppar[mi0*pstr], gv = pgrad[mi0*pstr];
    float pv2 = 0.f, gv2 = 0.f, fvv = 0.f;
    if (t == 0) { pv2 = b3[mi0*3+2]; gv2 = G6[mi0*3+2]; fvv = fv[mi0]; }
    int ss = stepsz[mi0];

    for (int m = blockIdx.x; m < Bn; m += stride) {
        // ---- SGD update from prefetched values ----
        const float lr = LRS[ss];
        float pw = pv - lr * gv;
        sP[t] = pw;
        out[(size_t)m*OSTR + t] = fminf(fmaxf(pw, -10000.f), 10000.f);
        if (t == 0) {
            float pw2 = pv2 - lr * gv2;
            sP[192] = pw2;
            out[(size_t)m*OSTR + 192] = fminf(fmaxf(pw2, -10000.f), 10000.f);
        }
        const float fvCur = fvv;

        // ---- prefetch next iteration (latency hides under this compute) ----
        {
            int mn = m + stride;
            size_t miN = (size_t)((mn < Bn) ? mn : m);
            pv = ppar[miN*pstr]; gv = pgrad[miN*pstr];
            if (t == 0) { pv2 = b3[miN*3+2]; gv2 = G6[miN*3+2]; fvv = fv[miN]; }
            ss = stepsz[miN];
        }
        __syncthreads();   // B1: sP ready; prev-iter MFMA reads of sT done

        // ================= fused forward + backward-dz: one point/thread ====
        float lossacc = 0.f, ssacc = 0.f;

        float h1v[10];
        #pragma unroll
        for (int j = 0; j < 10; j++) {
            f32x2 a = x01 * sP2[2*j] + x23 * sP2[2*j+1];
            float z = sP[40+j] + a.x + a.y;
            h1v[j] = fmaxf(z, 0.f);
        }
        f32x2 hh[5];
        #pragma unroll
        for (int p = 0; p < 5; p++) hh[p] = (f32x2){h1v[2*p], h1v[2*p+1]};

        float h2v[10];
        #pragma unroll
        for (int g = 0; g < 10; g++) {
            const f32x2* wr = sP2 + 25 + g*5;        // W2 row g (row-major)
            f32x2 a = hh[0]*wr[0] + hh[1]*wr[1];
            a += hh[2]*wr[2] + hh[3]*wr[3];
            a += hh[4]*wr[4];
            float z = sP[150+g] + a.x + a.y;
            h2v[g] = fmaxf(z, 0.f);
        }
        f32x2 h2h[5];
        #pragma unroll
        for (int p = 0; p < 5; p++) h2h[p] = (f32x2){h2v[2*p], h2v[2*p+1]};

        float lg[3];
        #pragma unroll
        for (int o = 0; o < 3; o++) {
            const f32x2* wr = sP2 + 80 + o*5;        // W3 row o
            f32x2 a = h2h[0]*wr[0] + h2h[1]*wr[1];
            a += h2h[2]*wr[2] + h2h[3]*wr[3];
            a += h2h[4]*wr[4];
            lg[o] = sP[190+o] + a.x + a.y;
        }

        float mx = fmaxf(lg[0], fmaxf(lg[1], lg[2]));
        float e0 = __expf(lg[0]-mx), e1 = __expf(lg[1]-mx), e2 = __expf(lg[2]-mx);
        float s   = e0 + e1 + e2;
        float inv = 1.f / s;
        float lse = mx + __logf(s);
        float ly  = (yv == 0) ? lg[0] : ((yv == 1) ? lg[1] : lg[2]);
        lossacc = act ? (lse - ly) : 0.f;

        float dl[3];
        dl[0] = (e0*inv - ((yv==0)?1.f:0.f)) * (1.f/150.f);
        dl[1] = (e1*inv - ((yv==1)?1.f:0.f)) * (1.f/150.f);
        dl[2] = (e2*inv - ((yv==2)?1.f:0.f)) * (1.f/150.f);

        // dz2[g] = sum_o dl[o]*W3[o][g], packed over g-pairs (row-major reads)
        f32x2 dz2a[5];
        #pragma unroll
        for (int p = 0; p < 5; p++) dz2a[p] = (f32x2){0.f, 0.f};
        #pragma unroll
        for (int o = 0; o < 3; o++) {
            f32x2 d = {dl[o], dl[o]};
            const f32x2* wr = sP2 + 80 + o*5;
            #pragma unroll
            for (int p = 0; p < 5; p++) dz2a[p] += d * wr[p];
        }
        float dz2v[10];
        #pragma unroll
        for (int g = 0; g < 10; g++) {
            float d = (g & 1) ? dz2a[g>>1].y : dz2a[g>>1].x;
            dz2v[g] = (h2v[g] > 0.f) ? d : 0.f;
        }

        // dz1[h] = sum_g dz2[g]*W2[g][h], g-outer so reads stay row-major
        f32x2 dz1a[5];
        #pragma unroll
        for (int p = 0; p < 5; p++) dz1a[p] = (f32x2){0.f, 0.f};
        #pragma unroll
        for (int g = 0; g < 10; g++) {
            f32x2 d = {dz2v[g], dz2v[g]};
            const f32x2* wr = sP2 + 25 + g*5;
            #pragma unroll
            for (int p = 0; p < 5; p++) dz1a[p] += d * wr[p];
        }
        float dz1v[10];
        #pragma unroll
        for (int h = 0; h < 10; h++) {
            float d = (h & 1) ? dz1a[h>>1].y : dz1a[h>>1].x;
            dz1v[h] = (h1v[h] > 0.f) ? d : 0.f;
        }

        if (act) {
            const int n = t;
            #pragma unroll
            for (int j = 0; j < 10; j++) sT[H1T  + j*KP + n] = __float2bfloat16(h1v[j]);
            #pragma unroll
            for (int g = 0; g < 10; g++) sT[H2T  + g*KP + n] = __float2bfloat16(h2v[g]);
            #pragma unroll
            for (int o = 0; o < 3;  o++) sT[DLT  + o*KP + n] = __float2bfloat16(dl[o]);
            #pragma unroll
            for (int g = 0; g < 10; g++) sT[DZ2T + g*KP + n] = __float2bfloat16(dz2v[g]);
            #pragma unroll
            for (int h = 0; h < 10; h++) sT[DZ1T + h*KP + n] = __float2bfloat16(dz1v[h]);
        }
        __syncthreads();   // B2: sT staged

        // ================= weight-grad GEMMs via MFMA: one tile per wave =====
        {
            f32x4 acc = {0.f, 0.f, 0.f, 0.f};
            #pragma unroll
            for (int kk = 0; kk < 5; kk++) {
                int k0 = kk*32 + q*8;
                short8 a = *(const short8*)(aptr + k0);
                short8 b = *(const short8*)(bptr + k0);
                acc = __builtin_amdgcn_mfma_f32_16x16x32_bf16(a, b, acc, 0, 0, 0);
            }
            #pragma unroll
            for (int r = 0; r < 4; r++) {
                if (valid[r]) {
                    float v = acc[r];
                    out[(size_t)m*OSTR + NPAR + offv[r]] = v;  // raw; kernel C scales
                    ssacc += v*v;
                }
            }
        }

        // ---- reductions: loss (all 3 waves), sumsq (per-wave tiles) ----
        #pragma unroll
        for (int off = 32; off > 0; off >>= 1) {
            lossacc += __shfl_down(lossacc, off, 64);
            ssacc   += __shfl_down(ssacc,   off, 64);
        }
        if (lane == 0) { red[w] = lossacc; red[4 + w] = ssacc; }
        __syncthreads();   // B3
        if (t == 0) {
            float blockss = red[4] + red[5] + red[6];
            if (storeMode) slots[1 + m] = blockss;
            else           atomicAdd(&slots[1 + (m & 1023)], blockss);
            float loss = (red[0] + red[1] + red[2]) * (1.f/150.f);
            out[(size_t)m*OSTR + 386] = loss;
            float imp = fvCur - loss;
            imp = fminf(fmaxf(imp, -10000.f), 10000.f);
            out[(size_t)m*OSTR + 387] = imp;
        }
    }
}

// Reduce slots[1..1+count) -> clip coef in slots[0].
__global__ __launch_bounds__(1024) void mlp_kernelB(float* __restrict__ slots, int count)
{
    int t = threadIdx.x;
    float v = 0.f;
    for (int i = t; i < count; i += 1024) v += slots[1 + i];
    #pragma unroll
    for (int off = 32; off > 0; off >>= 1) v += __shfl_down(v, off, 64);
    __shared__ float red[16];
    if ((t & 63) == 0) red[t >> 6] = v;
    __syncthreads();
    if (t == 0) {
        float total = 0.f;
        #pragma unroll
        for (int i = 0; i < 16; i++) total += red[i];
        slots[0] = fminf(1.f, 10.f / (sqrtf(total) + 1e-6f));
    }
}

__global__ __launch_bounds__(256) void mlp_kernelC(float* __restrict__ out,
                                                   const float* __restrict__ slots,
                                                   int total)
{
    float coef = slots[0];
    unsigned e = blockIdx.x * 256u + threadIdx.x;
    if (e < (unsigned)total) {
        unsigned m = e / 193u;
        unsigned i = e - m * 193u;
        size_t a = (size_t)m * OSTR + NPAR + i;
        out[a] *= coef;
    }
}

extern "C" void kernel_launch(void* const* d_in, const int* in_sizes, int n_in,
                              void* d_out, int out_size, void* d_ws, size_t ws_size,
                              hipStream_t stream) {
    const float* W1 = (const float*)d_in[0];
    const float* b1 = (const float*)d_in[1];
    const float* W2 = (const float*)d_in[2];
    const float* b2 = (const float*)d_in[3];
    const float* W3 = (const float*)d_in[4];
    const float* b3 = (const float*)d_in[5];
    const float* G1 = (const float*)d_in[6];
    const float* G2 = (const float*)d_in[7];
    const float* G3 = (const float*)d_in[8];
    const float* G4 = (const float*)d_in[9];
    const float* G5 = (const float*)d_in[10];
    const float* G6 = (const float*)d_in[11];
    const float* dx = (const float*)d_in[12];
    const float* fv = (const float*)d_in[13];
    const int*   dy = (const int*)d_in[14];
    const int*   st = (const int*)d_in[15];
    float* out   = (float*)d_out;
    float* slots = (float*)d_ws;

    int Bn = in_sizes[0] / 40;
    int storeMode = (ws_size >= (size_t)(Bn + 2) * sizeof(float)) ? 1 : 0;

    if (!storeMode) hipMemsetAsync(d_ws, 0, 4100, stream);
    int nb = (Bn < 2048) ? Bn : 2048;
    mlp_kernelA<<<nb, 192, 0, stream>>>(W1,b1,W2,b2,W3,b3,
                                        G1,G2,G3,G4,G5,G6,
                                        dx,fv,dy,st,out,slots,Bn,storeMode);
    mlp_kernelB<<<1, 1024, 0, stream>>>(slots, storeMode ? Bn : 1024);
    int total = Bn * NPAR;
    mlp_kernelC<<<(total + 255)/256, 256, 0, stream>>>(out, slots, total);
}

// Round 3
// 289.619 us; speedup vs baseline: 1.1044x; 1.1044x over previous
//
#include <hip/hip_runtime.h>
#include <hip/hip_bf16.h>

#define NPTS 150
#define KP   168          // padded K for MFMA; 5 K-steps of 32 cover 0..159
#define NPAR 193
#define OSTR 388

// bf16 transposed activation buffers, element offsets into sT
#define H1T  0            // [11][168]  rows 0..9 = h1^T, row 10 = ones (db2)
#define H2T  1848         // [11][168]  rows 0..9 = h2^T, row 10 = ones (db3)
#define XT   3696         // [5][168]   rows 0..3 = x^T,  row 4  = ones (db1)
#define DZ2T 4536         // [10][168]
#define DZ1T 6216         // [10][168]
#define DLT  7896         // [3][168]
#define TTOT 8400

typedef __attribute__((ext_vector_type(8))) short short8;
typedef __attribute__((ext_vector_type(4))) float f32x4;
typedef __attribute__((ext_vector_type(2))) float f32x2;

__constant__ float LRS[6] = {0.001f, 0.01f, 0.05f, 0.1f, 0.5f, 1.0f};

// One block per MLP (round-1 structure: short blocks ARE the latency hiding —
// round-2's persistent grid dropped occupancy 31.6->16.2% and VALUBusy 58->33%).
// Hot loops use float2 (v_pk_fma_f32) with row-major ds_read_b64 for h2, lg,
// dz2 AND dz1 (dz1 g-outer so it reads the same W2 rows as h2, no transpose).
__global__ __launch_bounds__(192)
__attribute__((amdgpu_waves_per_eu(2, 4)))
void mlp_kernelA(
    const float* __restrict__ W1, const float* __restrict__ b1,
    const float* __restrict__ W2, const float* __restrict__ b2,
    const float* __restrict__ W3, const float* __restrict__ b3,
    const float* __restrict__ G1, const float* __restrict__ G2,
    const float* __restrict__ G3, const float* __restrict__ G4,
    const float* __restrict__ G5, const float* __restrict__ G6,
    const float* __restrict__ dx, const float* __restrict__ fv,
    const int* __restrict__ dy, const int* __restrict__ stepsz,
    float* __restrict__ out, float* __restrict__ slots, int storeMode)
{
    const int m    = blockIdx.x;
    const int t    = threadIdx.x;
    const int lane = t & 63;
    const int w    = t >> 6;

    __shared__ alignas(16) __hip_bfloat16 sT[TTOT];
    __shared__ alignas(16) float sP[200];
    __shared__ float red[8];

    const float lr = LRS[stepsz[m]];

    // ---- SGD update: each thread computes param index t (t=0 also does 192) ----
    float pv;
    if      (t < 40)  pv = W1[m*40 + t]        - lr * G1[m*40 + t];
    else if (t < 50)  pv = b1[m*10 + (t-40)]   - lr * G2[m*10 + (t-40)];
    else if (t < 150) pv = W2[m*100 + (t-50)]  - lr * G3[m*100 + (t-50)];
    else if (t < 160) pv = b2[m*10 + (t-150)]  - lr * G4[m*10 + (t-150)];
    else if (t < 190) pv = W3[m*30 + (t-160)]  - lr * G5[m*30 + (t-160)];
    else              pv = b3[m*3 + (t-190)]   - lr * G6[m*3 + (t-190)];
    sP[t] = pv;
    out[(size_t)m*OSTR + t] = fminf(fmaxf(pv, -10000.f), 10000.f);
    if (t == 0) {
        float p192 = b3[m*3 + 2] - lr * G6[m*3 + 2];
        sP[192] = p192;
        out[(size_t)m*OSTR + 192] = fminf(fmaxf(p192, -10000.f), 10000.f);
    }

    // ---- zero the whole bf16 T-buffer (pad cols MUST be finite zeros:
    //      uninitialized LDS as bf16 can be Inf/NaN and 0*Inf = NaN in MFMA) ----
    {
        f32x4 z = {0.f, 0.f, 0.f, 0.f};
        f32x4* p = (f32x4*)sT;                 // 8400 bf16 = 1050 x 16B
        for (int i = t; i < 1050; i += 192) p[i] = z;
    }
    __syncthreads();

    // ---- ones rows (bias-grad columns) ----
    if (t < KP) {
        __hip_bfloat16 one = __float2bfloat16(1.0f);
        sT[H1T + 10*KP + t] = one;
        sT[H2T + 10*KP + t] = one;
        sT[XT  +  4*KP + t] = one;
    }
    // ---- x^T fill: x^T[f][n] = x[n][f] ----
    for (int i = t; i < 600; i += 192) {
        int n = i >> 2, f = i & 3;
        sT[XT + f*KP + n] = __float2bfloat16(dx[i]);
    }

    const f32x2* sP2 = (const f32x2*)sP;

    // ================= fused forward + backward-dz: ONE point per thread =====
    float lossacc = 0.f, ssacc = 0.f;
    {
        const int  n   = t;
        const bool act = (n < NPTS);
        const int  nc  = act ? n : 0;

        f32x4 xv = ((const f32x4*)dx)[nc];
        int   yv = dy[nc];
        const f32x2 x01 = {xv.x, xv.y}, x23 = {xv.z, xv.w};

        float h1v[10];
        #pragma unroll
        for (int j = 0; j < 10; j++) {
            f32x2 a = x01 * sP2[2*j] + x23 * sP2[2*j+1];
            float z = sP[40+j] + a.x + a.y;
            h1v[j] = fmaxf(z, 0.f);
        }
        f32x2 hh[5];
        #pragma unroll
        for (int p = 0; p < 5; p++) hh[p] = (f32x2){h1v[2*p], h1v[2*p+1]};

        float h2v[10];
        #pragma unroll
        for (int g = 0; g < 10; g++) {
            const f32x2* wr = sP2 + 25 + g*5;        // W2 row g (row-major)
            f32x2 a = hh[0]*wr[0] + hh[1]*wr[1];
            a += hh[2]*wr[2] + hh[3]*wr[3];
            a += hh[4]*wr[4];
            float z = sP[150+g] + a.x + a.y;
            h2v[g] = fmaxf(z, 0.f);
        }
        f32x2 h2h[5];
        #pragma unroll
        for (int p = 0; p < 5; p++) h2h[p] = (f32x2){h2v[2*p], h2v[2*p+1]};

        float lg[3];
        #pragma unroll
        for (int o = 0; o < 3; o++) {
            const f32x2* wr = sP2 + 80 + o*5;        // W3 row o
            f32x2 a = h2h[0]*wr[0] + h2h[1]*wr[1];
            a += h2h[2]*wr[2] + h2h[3]*wr[3];
            a += h2h[4]*wr[4];
            lg[o] = sP[190+o] + a.x + a.y;
        }

        float mx = fmaxf(lg[0], fmaxf(lg[1], lg[2]));
        float e0 = __expf(lg[0]-mx), e1 = __expf(lg[1]-mx), e2 = __expf(lg[2]-mx);
        float s   = e0 + e1 + e2;
        float inv = 1.f / s;
        float lse = mx + __logf(s);
        float ly  = (yv == 0) ? lg[0] : ((yv == 1) ? lg[1] : lg[2]);
        lossacc = act ? (lse - ly) : 0.f;

        float dl[3];
        dl[0] = (e0*inv - ((yv==0)?1.f:0.f)) * (1.f/150.f);
        dl[1] = (e1*inv - ((yv==1)?1.f:0.f)) * (1.f/150.f);
        dl[2] = (e2*inv - ((yv==2)?1.f:0.f)) * (1.f/150.f);

        // dz2[g] = sum_o dl[o]*W3[o][g], packed over g-pairs (row-major reads)
        f32x2 dz2a[5];
        #pragma unroll
        for (int p = 0; p < 5; p++) dz2a[p] = (f32x2){0.f, 0.f};
        #pragma unroll
        for (int o = 0; o < 3; o++) {
            f32x2 d = {dl[o], dl[o]};
            const f32x2* wr = sP2 + 80 + o*5;
            #pragma unroll
            for (int p = 0; p < 5; p++) dz2a[p] += d * wr[p];
        }
        float dz2v[10];
        #pragma unroll
        for (int g = 0; g < 10; g++) {
            float d = (g & 1) ? dz2a[g>>1].y : dz2a[g>>1].x;
            dz2v[g] = (h2v[g] > 0.f) ? d : 0.f;
        }

        // dz1[h] = sum_g dz2[g]*W2[g][h], g-outer so reads stay row-major
        f32x2 dz1a[5];
        #pragma unroll
        for (int p = 0; p < 5; p++) dz1a[p] = (f32x2){0.f, 0.f};
        #pragma unroll
        for (int g = 0; g < 10; g++) {
            f32x2 d = {dz2v[g], dz2v[g]};
            const f32x2* wr = sP2 + 25 + g*5;
            #pragma unroll
            for (int p = 0; p < 5; p++) dz1a[p] += d * wr[p];
        }
        float dz1v[10];
        #pragma unroll
        for (int h = 0; h < 10; h++) {
            float d = (h & 1) ? dz1a[h>>1].y : dz1a[h>>1].x;
            dz1v[h] = (h1v[h] > 0.f) ? d : 0.f;
        }

        if (act) {
            #pragma unroll
            for (int j = 0; j < 10; j++) sT[H1T  + j*KP + n] = __float2bfloat16(h1v[j]);
            #pragma unroll
            for (int g = 0; g < 10; g++) sT[H2T  + g*KP + n] = __float2bfloat16(h2v[g]);
            #pragma unroll
            for (int o = 0; o < 3;  o++) sT[DLT  + o*KP + n] = __float2bfloat16(dl[o]);
            #pragma unroll
            for (int g = 0; g < 10; g++) sT[DZ2T + g*KP + n] = __float2bfloat16(dz2v[g]);
            #pragma unroll
            for (int h = 0; h < 10; h++) sT[DZ1T + h*KP + n] = __float2bfloat16(dz1v[h]);
        }
    }
    __syncthreads();

    // ================= weight-grad GEMMs via MFMA: one tile per wave =========
    {
        const short* sTs = reinterpret_cast<const short*>(sT);
        const int mrow = lane & 15, q = lane >> 4;

        int abase, arows, bbase, bcols, woff, nW, boff;
        if      (w == 0) { abase=DZ2T; arows=10; bbase=H1T; bcols=11; woff=50;  nW=10; boff=150; }
        else if (w == 1) { abase=DZ1T; arows=10; bbase=XT;  bcols=5;  woff=0;   nW=4;  boff=40;  }
        else             { abase=DLT;  arows=3;  bbase=H2T; bcols=11; woff=160; nW=10; boff=190; }

        int ar = (mrow < arows) ? mrow : 0;
        int br = (mrow < bcols) ? mrow : 0;
        f32x4 acc = {0.f, 0.f, 0.f, 0.f};
        #pragma unroll
        for (int kk = 0; kk < 5; kk++) {
            int k0 = kk*32 + q*8;
            short8 a = *(const short8*)(sTs + abase + ar*KP + k0);
            short8 b = *(const short8*)(sTs + bbase + br*KP + k0);
            acc = __builtin_amdgcn_mfma_f32_16x16x32_bf16(a, b, acc, 0, 0, 0);
        }
        #pragma unroll
        for (int r = 0; r < 4; r++) {
            int row = q*4 + r;
            if (row < arows && mrow < bcols) {
                float v = acc[r];
                int off = (mrow < nW) ? (woff + row*nW + mrow) : (boff + row);
                out[(size_t)m*OSTR + NPAR + off] = v;   // raw grad; kernel C scales
                ssacc += v*v;
            }
        }
    }

    // ---- reductions: loss (across all 3 waves), sumsq (per-wave tiles) ----
    #pragma unroll
    for (int off = 32; off > 0; off >>= 1) {
        lossacc += __shfl_down(lossacc, off, 64);
        ssacc   += __shfl_down(ssacc,   off, 64);
    }
    if (lane == 0) { red[w] = lossacc; red[4 + w] = ssacc; }
    __syncthreads();
    if (t == 0) {
        float blockss = red[4] + red[5] + red[6];
        if (storeMode) slots[1 + m] = blockss;            // no memset needed
        else           atomicAdd(&slots[1 + (m & 1023)], blockss);
        float loss = (red[0] + red[1] + red[2]) * (1.f/150.f);
        out[(size_t)m*OSTR + 386] = loss;
        float imp = fv[m] - loss;
        imp = fminf(fmaxf(imp, -10000.f), 10000.f);
        out[(size_t)m*OSTR + 387] = imp;
    }
}

// Multi-block reduction slots[1..1+count) -> raw total sumsq into slots[0]
// (round-1 kernelB was ONE block serially streaming 131 KB: ~25-30 us of the
// 108 us non-kernelA time. 64 blocks + one f32 atomicAdd each ~ 4 us.)
__global__ __launch_bounds__(256) void mlp_kernelB(float* __restrict__ slots, int count)
{
    int idx = blockIdx.x * 256 + threadIdx.x;
    int stride = gridDim.x * 256;
    float v = 0.f;
    for (int i = idx; i < count; i += stride) v += slots[1 + i];
    #pragma unroll
    for (int off = 32; off > 0; off >>= 1) v += __shfl_down(v, off, 64);
    __shared__ float red[4];
    int t = threadIdx.x;
    if ((t & 63) == 0) red[t >> 6] = v;
    __syncthreads();
    if (t == 0) {
        float total = red[0] + red[1] + red[2] + red[3];
        atomicAdd(&slots[0], total);
    }
}

// One block per MLP, coalesced scalar RMW over the 193 grad slots; coef
// derived in-register from the raw total (no second reduction kernel).
__global__ __launch_bounds__(192) void mlp_kernelC(float* __restrict__ out,
                                                   const float* __restrict__ slots)
{
    float total = slots[0];
    float coef = fminf(1.f, 10.f / (sqrtf(total) + 1e-6f));
    size_t base = (size_t)blockIdx.x * OSTR + NPAR;
    int t = threadIdx.x;
    out[base + t] *= coef;
    if (t == 0) out[base + 192] *= coef;
}

extern "C" void kernel_launch(void* const* d_in, const int* in_sizes, int n_in,
                              void* d_out, int out_size, void* d_ws, size_t ws_size,
                              hipStream_t stream) {
    const float* W1 = (const float*)d_in[0];
    const float* b1 = (const float*)d_in[1];
    const float* W2 = (const float*)d_in[2];
    const float* b2 = (const float*)d_in[3];
    const float* W3 = (const float*)d_in[4];
    const float* b3 = (const float*)d_in[5];
    const float* G1 = (const float*)d_in[6];
    const float* G2 = (const float*)d_in[7];
    const float* G3 = (const float*)d_in[8];
    const float* G4 = (const float*)d_in[9];
    const float* G5 = (const float*)d_in[10];
    const float* G6 = (const float*)d_in[11];
    const float* dx = (const float*)d_in[12];
    const float* fv = (const float*)d_in[13];
    const int*   dy = (const int*)d_in[14];
    const int*   st = (const int*)d_in[15];
    float* out   = (float*)d_out;
    float* slots = (float*)d_ws;

    int Bn = in_sizes[0] / 40;
    int storeMode = (ws_size >= (size_t)(Bn + 2) * sizeof(float)) ? 1 : 0;

    if (storeMode) hipMemsetAsync(d_ws, 0, 4, stream);       // just slots[0]
    else           hipMemsetAsync(d_ws, 0, 4100, stream);    // slots[0..1024]
    mlp_kernelA<<<Bn, 192, 0, stream>>>(W1,b1,W2,b2,W3,b3,
                                        G1,G2,G3,G4,G5,G6,
                                        dx,fv,dy,st,out,slots,storeMode);
    mlp_kernelB<<<64, 256, 0, stream>>>(slots, storeMode ? Bn : 1024);
    mlp_kernelC<<<Bn, 192, 0, stream>>>(out, slots);
}